// Round 13
// baseline (265.731 us; speedup 1.0000x reference)
//
#include <hip/hip_runtime.h>
#include <math.h>

#define NPCH 49
#define NA 18
#define NB 8192
#define TOTAL (NB*NPCH)    // 401408
#define NBLK (TOTAL/64)    // 6272 cross-image blocks (64 rows each, all valid)

typedef __attribute__((ext_vector_type(8))) short bf16x8;
typedef __attribute__((ext_vector_type(4))) float f32x4;

__device__ __forceinline__ unsigned short f2bf(float f) {
    unsigned int u = __float_as_uint(f);
    return (unsigned short)((u + 0x7FFFu + ((u >> 16) & 1u)) >> 16);
}

#define MF(a,b,c) __builtin_amdgcn_mfma_f32_16x16x32_bf16((a),(b),(c),0,0,0)
#define RAWBAR() do { \
    asm volatile("s_waitcnt lgkmcnt(0)" ::: "memory"); \
    __builtin_amdgcn_s_barrier(); \
    asm volatile("" ::: "memory"); \
} while (0)

// ---------------------------------------------------------------------------
// Weight stream (validated layout, unchanged): 256 frags x 512 ushort.
// Frag fs element (l,j) = W[k0+(l>>4)*8+j][n0+(l&15)]
//  fs   0..19 : a1   s=fs>>2, w=fs&3   (k<144 ? Wa1 : 0)
//  fs  20..27 : a2   s=(fs-20)>>2, w=&3
//  fs  32..175: e1   q=fs-32: s=q>>4, nt=(q>>2)&3, w=q&3
//  fs 176..239: e2   q=fs-176: s=q>>3, nt=(q>>2)&1, w=q&3
//  fs 240..247: e3   q=fs-240: s=q>>1, nt=q&1 (n>=18 -> 0)
// ---------------------------------------------------------------------------
#define WS_US (256*512)

__global__ __launch_bounds__(256)
void prep_weights(const float* __restrict__ We1, const float* __restrict__ We2,
                  const float* __restrict__ We3, const float* __restrict__ Wa1,
                  const float* __restrict__ Wa2, unsigned short* __restrict__ wst)
{
    int i = blockIdx.x * 256 + threadIdx.x;
    if (i >= WS_US) return;
    const int fs = i >> 9, l = (i >> 3) & 63, j = i & 7;
    const int kh = ((l >> 4) << 3) + j;
    const int nl = l & 15;
    float v = 0.0f;
    if (fs < 20) {
        int s = fs >> 2, w = fs & 3;
        int k = s * 32 + kh, n = w * 16 + nl;
        v = (k < 144) ? Wa1[k * 64 + n] : 0.0f;
    } else if (fs < 28) {
        int q = fs - 20, s = q >> 2, w = q & 3;
        v = Wa2[(s * 32 + kh) * 64 + (w * 16 + nl)];
    } else if (fs < 32) {
        v = 0.0f;
    } else if (fs < 176) {
        int q = fs - 32, s = q >> 4, nt = (q >> 2) & 3, w = q & 3;
        v = We1[(s * 32 + kh) * 256 + (w * 64 + nt * 16 + nl)];
    } else if (fs < 240) {
        int q = fs - 176, s = q >> 3, nt = (q >> 2) & 1, w = q & 3;
        v = We2[(s * 32 + kh) * 128 + (w * 32 + nt * 16 + nl)];
    } else if (fs < 248) {
        int q = fs - 240, s = q >> 1, nt = q & 1;
        int n = nt * 16 + nl;
        v = (n < NA) ? We3[(s * 32 + kh) * NA + n] : 0.0f;
    }
    wst[i] = f2bf(v);
}

// relu + pack + 4 b16 stores at base[0],[8],[16],[24]
__device__ __forceinline__ void wb_frag(unsigned short* base, f32x4 a)
{
    float r0 = fmaxf(a[0], 0.f), r1 = fmaxf(a[1], 0.f);
    float r2 = fmaxf(a[2], 0.f), r3 = fmaxf(a[3], 0.f);
    unsigned u01, u23;
    asm("v_cvt_pk_bf16_f32 %0, %1, %2" : "=v"(u01) : "v"(r0), "v"(r1));
    asm("v_cvt_pk_bf16_f32 %0, %1, %2" : "=v"(u23) : "v"(r2), "v"(r3));
    base[0]  = (unsigned short)u01;
    base[8]  = (unsigned short)(u01 >> 16);
    base[16] = (unsigned short)u23;
    base[24] = (unsigned short)(u23 >> 16);
}

// ---------------------------------------------------------------------------
// Fused kernel: R10 structure (validated best, 227us): 256 threads / 4 waves,
// 64-row cross-image blocks, register weight prefetch, 6 raw barriers.
// R13 changes: (1) fast __expf/__logf, (2) staging divides hoisted once per
// thread (thread = row*4sub; 9 loads at compile-time offsets).
// LDS (46080 B, 3 blocks/CU):
//   Ein [0,36864) | H1 overlays [0,32768) | H2 overlays [0,16384)
//   HA1 [36864,45056) | APT [45056,46080)
// ---------------------------------------------------------------------------
__global__ __launch_bounds__(256, 3)
void fused_mfma_kernel(const float* __restrict__ last_s, const float* __restrict__ now_s,
                       const unsigned short* __restrict__ wstream,
                       const float* __restrict__ be1, const float* __restrict__ be2,
                       const float* __restrict__ be3, const float* __restrict__ ba1,
                       const float* __restrict__ ba2, const float* __restrict__ ba3,
                       const float* __restrict__ Wa3,
                       float* __restrict__ out_each, float* __restrict__ ws_alpha)
{
    __shared__ __align__(16) unsigned char smem[46080];
    unsigned short* Ein = (unsigned short*)smem;            // [4mt][9s][512]
    unsigned short* H1  = (unsigned short*)smem;            // [4mt][8s][512]
    unsigned short* H2  = (unsigned short*)smem;            // [4mt][4s][512]
    unsigned short* HA1 = (unsigned short*)(smem + 36864);  // [4mt][2s][512]
    float*          APT = (float*)(smem + 45056);           // [4][64]

    const int t    = threadIdx.x;
    const int lane = t & 63;
    const int wid  = t >> 6;
    const int g    = lane >> 4;
    const int rl   = lane & 15;
    const int row0 = blockIdx.x * 64;

#define GFRAG(fs) (*(const bf16x8*)(wstream + (size_t)(fs) * 512 + lane * 8))

    // ---- prefetch alpha + first e1 weight frags (fly during image staging) ----
    bf16x8 wa1f[5], wa2f[2];
    #pragma unroll
    for (int s = 0; s < 5; ++s) wa1f[s] = GFRAG(s * 4 + wid);
    #pragma unroll
    for (int s = 0; s < 2; ++s) wa2f[s] = GFRAG(20 + s * 4 + wid);
    bf16x8 wA[4], wB[4], wC[4];
    #pragma unroll
    for (int nt = 0; nt < 4; ++nt) wA[nt] = GFRAG(32 + 0 * 16 + nt * 4 + wid);
    #pragma unroll
    for (int nt = 0; nt < 4; ++nt) wB[nt] = GFRAG(32 + 1 * 16 + nt * 4 + wid);
    #pragma unroll
    for (int nt = 0; nt < 4; ++nt) wC[nt] = GFRAG(32 + 2 * 16 + nt * 4 + wid);

    // ---- phase 0: patch gather -> Ein fragment layout ----
    // thread = (row r = t>>2, sub = t&3); divides once per thread; the 9
    // float4-loads are compile-time offsets from one patch-row base pointer.
    {
        const int r   = t >> 2;          // 0..63
        const int sub = t & 3;           // covers q = sub*9 .. sub*9+8
        const int R   = row0 + r;
        const int im  = R / 49;
        const int p   = R - im * 49;
        const int pi  = p / 7, pj = p - pi * 7;
        const int wp  = r >> 4, rp = r & 15;
        const size_t pbase = (size_t)im * 7056 + (pi * 12 + sub * 3) * 84 + pj * 12;
        const float* nptr = now_s  + pbase;
        const float* lptr = last_s + pbase;
        const int fbase = sub * 36;      // feature index base for this thread
        #pragma unroll
        for (int k = 0; k < 9; ++k) {
            const int fro = k / 3;       // compile-time: 0,0,0,1,1,1,2,2,2
            const int fc4 = k - fro * 3; // compile-time: 0,1,2,...
            const float4 n4 = *(const float4*)(nptr + fro * 84 + fc4 * 4);
            const float4 l4 = *(const float4*)(lptr + fro * 84 + fc4 * 4);
            const float k255 = 1.0f / 255.0f;
            float d0 = (n4.x - l4.x) * k255, d1 = (n4.y - l4.y) * k255;
            float d2 = (n4.z - l4.z) * k255, d3 = (n4.w - l4.w) * k255;
            float w0 = n4.x * k255, w1 = n4.y * k255;
            float w2 = n4.z * k255, w3 = n4.w * k255;
            unsigned da, db, wa, wb;
            asm("v_cvt_pk_bf16_f32 %0, %1, %2" : "=v"(da) : "v"(d0), "v"(d1));
            asm("v_cvt_pk_bf16_f32 %0, %1, %2" : "=v"(db) : "v"(d2), "v"(d3));
            asm("v_cvt_pk_bf16_f32 %0, %1, %2" : "=v"(wa) : "v"(w0), "v"(w1));
            asm("v_cvt_pk_bf16_f32 %0, %1, %2" : "=v"(wb) : "v"(w2), "v"(w3));
            const int f  = fbase + fro * 12 + fc4 * 4;     // sub*36 + const
            const int s1 = f >> 5, g1 = (f >> 3) & 3, j1 = f & 7;
            *(uint2*)(Ein + (wp * 9 + s1) * 512 + g1 * 128 + rp * 8 + j1) = (uint2){da, db};
            const int k2 = 144 + f;
            const int s2 = k2 >> 5, g2 = (k2 >> 3) & 3, j2 = k2 & 7;
            *(uint2*)(Ein + (wp * 9 + s2) * 512 + g2 * 128 + rp * 8 + j2) = (uint2){wa, wb};
        }
    }
    RAWBAR();   // B1: Ein ready (all 64 rows valid)

    // ================= alpha layer 1 (no barrier after; e1 follows) =========
    const int colA = wid * 16 + rl;
    {
        const float b1 = ba1[colA];
        f32x4 accA[4];
        #pragma unroll
        for (int mt = 0; mt < 4; ++mt) accA[mt] = (f32x4){b1, b1, b1, b1};
        #pragma unroll
        for (int sa = 0; sa < 5; ++sa) {
            int ok = 144 + sa * 32 + g * 8;
            if (ok > 280) ok = 280;   // tail: weight rows zero; clamp into valid data
            #pragma unroll
            for (int mt = 0; mt < 4; ++mt) {
                const bf16x8 af = *(const bf16x8*)(Ein + (mt * 9 + (ok >> 5)) * 512 +
                                                   ((ok >> 3) & 3) * 128 + rl * 8);
                accA[mt] = MF(af, wa1f[sa], accA[mt]);
            }
        }
        const int sA  = wid >> 1;
        const int hiA = (wid & 1) * 2 + (rl >> 3);
        const int jA  = rl & 7;
        #pragma unroll
        for (int mt = 0; mt < 4; ++mt)
            wb_frag(HA1 + (mt * 2 + sA) * 512 + hiA * 128 + g * 32 + jA, accA[mt]);
    }

    // ================= e layer 1 part 1 (steps 0..4) =================
    f32x4 acc1[4][4];
    #pragma unroll
    for (int nt = 0; nt < 4; ++nt) {
        const float b = be1[wid * 64 + nt * 16 + rl];
        #pragma unroll
        for (int mt = 0; mt < 4; ++mt) acc1[mt][nt] = (f32x4){b, b, b, b};
    }

#define E1_STEP(W, s, sn) do { \
    const bf16x8 x0_ = *(const bf16x8*)(Ein + (0 * 9 + (s)) * 512 + lane * 8); \
    const bf16x8 x1_ = *(const bf16x8*)(Ein + (1 * 9 + (s)) * 512 + lane * 8); \
    const bf16x8 x2_ = *(const bf16x8*)(Ein + (2 * 9 + (s)) * 512 + lane * 8); \
    const bf16x8 x3_ = *(const bf16x8*)(Ein + (3 * 9 + (s)) * 512 + lane * 8); \
    _Pragma("unroll") \
    for (int nt = 0; nt < 4; ++nt) { \
        acc1[0][nt] = MF(x0_, W[nt], acc1[0][nt]); \
        acc1[1][nt] = MF(x1_, W[nt], acc1[1][nt]); \
        acc1[2][nt] = MF(x2_, W[nt], acc1[2][nt]); \
        acc1[3][nt] = MF(x3_, W[nt], acc1[3][nt]); \
    } \
    if ((sn) <= 8) { \
        _Pragma("unroll") \
        for (int nt = 0; nt < 4; ++nt) W[nt] = GFRAG(32 + (sn) * 16 + nt * 4 + wid); \
    } \
} while (0)

    E1_STEP(wA, 0, 3); E1_STEP(wB, 1, 4); E1_STEP(wC, 2, 5);
    E1_STEP(wA, 3, 6); E1_STEP(wB, 4, 7);

    RAWBAR();   // B2: HA1 visible (issued after 5 e1 steps of useful work)

    // ================= alpha layer 2 + fused layer 3 =================
    {
        const float b2 = ba2[colA];
        const float w3 = Wa3[colA];
        f32x4 accB[4];
        #pragma unroll
        for (int mt = 0; mt < 4; ++mt) accB[mt] = (f32x4){b2, b2, b2, b2};
        #pragma unroll
        for (int s = 0; s < 2; ++s) {
            #pragma unroll
            for (int mt = 0; mt < 4; ++mt) {
                const bf16x8 af = *(const bf16x8*)(HA1 + (mt * 2 + s) * 512 + lane * 8);
                accB[mt] = MF(af, wa2f[s], accB[mt]);
            }
        }
        #pragma unroll
        for (int mt = 0; mt < 4; ++mt) {
            #pragma unroll
            for (int r = 0; r < 4; ++r) {
                float v = fmaxf(accB[mt][r], 0.0f) * w3;
                v += __shfl_xor(v, 1); v += __shfl_xor(v, 2);
                v += __shfl_xor(v, 4); v += __shfl_xor(v, 8);
                if (rl == 0) APT[wid * 64 + mt * 16 + g * 4 + r] = v;
            }
        }
    }

    // ================= e layer 1 part 2 (steps 5..8) =================
    E1_STEP(wC, 5, 8); E1_STEP(wA, 6, 9); E1_STEP(wB, 7, 9); E1_STEP(wC, 8, 9);
#undef E1_STEP

    // e2 weight prefetch (flies across B3 + H1 writes + B4)
    bf16x8 vA[2], vB[2], vC[2];
    #pragma unroll
    for (int nt = 0; nt < 2; ++nt) vA[nt] = GFRAG(176 + 0 * 8 + nt * 4 + wid);
    #pragma unroll
    for (int nt = 0; nt < 2; ++nt) vB[nt] = GFRAG(176 + 1 * 8 + nt * 4 + wid);
    #pragma unroll
    for (int nt = 0; nt < 2; ++nt) vC[nt] = GFRAG(176 + 2 * 8 + nt * 4 + wid);

    RAWBAR();   // B3: APT visible + all Ein reads done -> H1 may overlay

    // alpha logits -> ws_alpha (all 64 rows valid, global flattened index)
    if (t < 64)
        ws_alpha[row0 + t] = APT[t] + APT[64 + t] + APT[128 + t] + APT[192 + t] + ba3[0];

    // H1 fragment writes (relu, cvt_pk)
    #pragma unroll
    for (int mt = 0; mt < 4; ++mt) {
        #pragma unroll
        for (int nt = 0; nt < 4; ++nt) {
            const int col = wid * 64 + nt * 16 + rl;
            wb_frag(H1 + (mt * 8 + (col >> 5)) * 512 + ((col >> 3) & 3) * 128 +
                    g * 32 + (col & 7), acc1[mt][nt]);
        }
    }
    RAWBAR();   // B4: H1 ready

    // ================= e layer 2: 256 -> 128 =================
    f32x4 acc2[4][2];
    #pragma unroll
    for (int nt = 0; nt < 2; ++nt) {
        const float b = be2[wid * 32 + nt * 16 + rl];
        #pragma unroll
        for (int mt = 0; mt < 4; ++mt) acc2[mt][nt] = (f32x4){b, b, b, b};
    }

#define E2_STEP(V, s2, sn) do { \
    const bf16x8 x0_ = *(const bf16x8*)(H1 + (0 * 8 + (s2)) * 512 + lane * 8); \
    const bf16x8 x1_ = *(const bf16x8*)(H1 + (1 * 8 + (s2)) * 512 + lane * 8); \
    const bf16x8 x2_ = *(const bf16x8*)(H1 + (2 * 8 + (s2)) * 512 + lane * 8); \
    const bf16x8 x3_ = *(const bf16x8*)(H1 + (3 * 8 + (s2)) * 512 + lane * 8); \
    _Pragma("unroll") \
    for (int nt = 0; nt < 2; ++nt) { \
        acc2[0][nt] = MF(x0_, V[nt], acc2[0][nt]); \
        acc2[1][nt] = MF(x1_, V[nt], acc2[1][nt]); \
        acc2[2][nt] = MF(x2_, V[nt], acc2[2][nt]); \
        acc2[3][nt] = MF(x3_, V[nt], acc2[3][nt]); \
    } \
    if ((sn) <= 7) { \
        _Pragma("unroll") \
        for (int nt = 0; nt < 2; ++nt) V[nt] = GFRAG(176 + (sn) * 8 + nt * 4 + wid); \
    } \
} while (0)

    E2_STEP(vA, 0, 3); E2_STEP(vB, 1, 4); E2_STEP(vC, 2, 5);
    E2_STEP(vA, 3, 6); E2_STEP(vB, 4, 7); E2_STEP(vC, 5, 8);
    E2_STEP(vA, 6, 8); E2_STEP(vB, 7, 8);
#undef E2_STEP

    // e3 weight frags (in flight across barriers)
    bf16x8 w3f[8];
    #pragma unroll
    for (int q = 0; q < 8; ++q) w3f[q] = GFRAG(240 + q);

    RAWBAR();   // B5: all H1 reads done -> H2 may overlay

    // H2 fragment writes (relu, cvt_pk)
    #pragma unroll
    for (int mt = 0; mt < 4; ++mt) {
        #pragma unroll
        for (int nt = 0; nt < 2; ++nt) {
            const int c2 = nt * 16 + rl;
            wb_frag(H2 + (mt * 4 + wid) * 512 + ((c2 >> 3) & 3) * 128 +
                    g * 32 + (c2 & 7), acc2[mt][nt]);
        }
    }
    RAWBAR();   // B6: H2 ready

    // ================= e layer 3: 128 -> 18 (+log_softmax) =================
    {
        f32x4 acc3[2];
        #pragma unroll
        for (int nt = 0; nt < 2; ++nt) {
            const int col = nt * 16 + rl;
            const float b = (col < NA) ? be3[col] : 0.0f;
            acc3[nt] = (f32x4){b, b, b, b};
        }
        #pragma unroll
        for (int s = 0; s < 4; ++s) {
            const bf16x8 af = *(const bf16x8*)(H2 + (wid * 4 + s) * 512 + lane * 8);
            acc3[0] = MF(af, w3f[s * 2 + 0], acc3[0]);
            acc3[1] = MF(af, w3f[s * 2 + 1], acc3[1]);
        }
        const bool v1 = (rl < 2);
        #pragma unroll
        for (int r = 0; r < 4; ++r) {
            const int prow = row0 + wid * 16 + g * 4 + r;   // always valid
            float x0 = acc3[0][r];
            float x1 = acc3[1][r];
            float m = fmaxf(x0, v1 ? x1 : -3.0e38f);
            m = fmaxf(m, __shfl_xor(m, 1)); m = fmaxf(m, __shfl_xor(m, 2));
            m = fmaxf(m, __shfl_xor(m, 4)); m = fmaxf(m, __shfl_xor(m, 8));
            float sm = __expf(x0 - m) + (v1 ? __expf(x1 - m) : 0.0f);
            sm += __shfl_xor(sm, 1); sm += __shfl_xor(sm, 2);
            sm += __shfl_xor(sm, 4); sm += __shfl_xor(sm, 8);
            const float L = m + __logf(sm);
            float* o = out_each + (size_t)prow * NA;
            o[rl] = x0 - L;
            if (v1) o[16 + rl] = x1 - L;
        }
    }
#undef GFRAG
}

// ---------------------------------------------------------------------------
// Per-image alpha combine (validated structure; fast transcendentals).
// ---------------------------------------------------------------------------
__global__ __launch_bounds__(64)
void alpha_combine_kernel(const float* __restrict__ ws_alpha,
                          const float* __restrict__ out_each,
                          float* __restrict__ out_probs,
                          float* __restrict__ ws_ent)
{
    const int b = blockIdx.x;
    const int lane = threadIdx.x;

    float lg = (lane < NPCH) ? ws_alpha[b * NPCH + lane] : -3.0e38f;
    float m = lg;
    #pragma unroll
    for (int off = 32; off > 0; off >>= 1) m = fmaxf(m, __shfl_xor(m, off, 64));
    float ex = (lane < NPCH) ? __expf(lg - m) : 0.0f;
    float s = ex;
    #pragma unroll
    for (int off = 32; off > 0; off >>= 1) s += __shfl_xor(s, off, 64);
    const float ls = __logf(s);
    const float alpha = ex / s;

    float ent = (lane < NPCH) ? alpha * (lg - m - ls) : 0.0f;
    #pragma unroll
    for (int off = 32; off > 0; off >>= 1) ent += __shfl_xor(ent, off, 64);
    if (lane == 0) ws_ent[b] = ent;

    float acc = 0.0f;
    const float* eb = out_each + (size_t)b * NPCH * NA;
    for (int p = 0; p < NPCH; ++p) {
        const float ap = __shfl(alpha, p, 64);
        if (lane < NA) acc += ap * eb[p * NA + lane];
    }
    float mm = (lane < NA) ? acc : -3.0e38f;
    #pragma unroll
    for (int off = 32; off > 0; off >>= 1) mm = fmaxf(mm, __shfl_xor(mm, off, 64));
    float ee = (lane < NA) ? __expf(acc - mm) : 0.0f;
    #pragma unroll
    for (int off = 32; off > 0; off >>= 1) ee += __shfl_xor(ee, off, 64);
    if (lane < NA) out_probs[b * NA + lane] = acc - mm - __logf(ee);
}

__global__ __launch_bounds__(256)
void ent_reduce_kernel(const float* __restrict__ ws_ent, float* __restrict__ out_scalar)
{
    float s = 0.0f;
    for (int i = threadIdx.x; i < NB; i += 256) s += ws_ent[i];
    #pragma unroll
    for (int off = 32; off > 0; off >>= 1) s += __shfl_xor(s, off, 64);
    __shared__ float ps[4];
    if ((threadIdx.x & 63) == 0) ps[threadIdx.x >> 6] = s;
    __syncthreads();
    if (threadIdx.x == 0)
        out_scalar[0] = (ps[0] + ps[1] + ps[2] + ps[3]) * (1.0f / NB);
}

extern "C" void kernel_launch(void* const* d_in, const int* in_sizes, int n_in,
                              void* d_out, int out_size, void* d_ws, size_t ws_size,
                              hipStream_t stream)
{
    (void)in_sizes; (void)n_in; (void)out_size; (void)ws_size;

    const float* last_s = (const float*)d_in[0];
    const float* now_s  = (const float*)d_in[1];
    const float* We1 = (const float*)d_in[2];  const float* be1 = (const float*)d_in[3];
    const float* We2 = (const float*)d_in[4];  const float* be2 = (const float*)d_in[5];
    const float* We3 = (const float*)d_in[6];  const float* be3 = (const float*)d_in[7];
    const float* Wa1 = (const float*)d_in[8];  const float* ba1 = (const float*)d_in[9];
    const float* Wa2 = (const float*)d_in[10]; const float* ba2 = (const float*)d_in[11];
    const float* Wa3 = (const float*)d_in[12]; const float* ba3 = (const float*)d_in[13];

    float* out = (float*)d_out;
    float* out_probs = out;                    // [B,18]
    float* out_ent   = out + NB * NA;          // scalar
    float* out_each  = out + NB * NA + 1;      // [B,49,18]

    float* ws_alpha = (float*)d_ws;                          // [TOTAL]
    float* ws_ent   = ws_alpha + TOTAL;                      // [NB]
    unsigned short* wst = (unsigned short*)(ws_ent + NB);    // weight stream (256KB)

    prep_weights<<<dim3((WS_US + 255) / 256), dim3(256), 0, stream>>>(
        We1, We2, We3, Wa1, Wa2, wst);

    fused_mfma_kernel<<<dim3(NBLK), dim3(256), 0, stream>>>(
        last_s, now_s, wst, be1, be2, be3, ba1, ba2, ba3, Wa3,
        out_each, ws_alpha);

    alpha_combine_kernel<<<dim3(NB), dim3(64), 0, stream>>>(
        ws_alpha, out_each, out_probs, ws_ent);

    ent_reduce_kernel<<<dim3(1), dim3(256), 0, stream>>>(ws_ent, out_ent);
}

// Round 14
// 225.087 us; speedup vs baseline: 1.1806x; 1.1806x over previous
//
#include <hip/hip_runtime.h>
#include <math.h>

#define NPCH 49
#define NA 18
#define NB 8192
#define TOTAL (NB*NPCH)    // 401408
#define NBLK (TOTAL/64)    // 6272 cross-image blocks (64 rows each, all valid)

typedef __attribute__((ext_vector_type(8))) short bf16x8;
typedef __attribute__((ext_vector_type(4))) float f32x4;

__device__ __forceinline__ unsigned short f2bf(float f) {
    unsigned int u = __float_as_uint(f);
    return (unsigned short)((u + 0x7FFFu + ((u >> 16) & 1u)) >> 16);
}

#define MF(a,b,c) __builtin_amdgcn_mfma_f32_16x16x32_bf16((a),(b),(c),0,0,0)
#define RAWBAR() do { \
    asm volatile("s_waitcnt lgkmcnt(0)" ::: "memory"); \
    __builtin_amdgcn_s_barrier(); \
    asm volatile("" ::: "memory"); \
} while (0)

// ---------------------------------------------------------------------------
// Weight stream (validated layout, unchanged): 256 frags x 512 ushort.
// Frag fs element (l,j) = W[k0+(l>>4)*8+j][n0+(l&15)]
//  fs   0..19 : a1   s=fs>>2, w=fs&3   (k<144 ? Wa1 : 0)
//  fs  20..27 : a2   s=(fs-20)>>2, w=&3
//  fs  32..175: e1   q=fs-32: s=q>>4, nt=(q>>2)&3, w=q&3
//  fs 176..239: e2   q=fs-176: s=q>>3, nt=(q>>2)&1, w=q&3
//  fs 240..247: e3   q=fs-240: s=q>>1, nt=q&1 (n>=18 -> 0)
// ---------------------------------------------------------------------------
#define WS_US (256*512)

__global__ __launch_bounds__(256)
void prep_weights(const float* __restrict__ We1, const float* __restrict__ We2,
                  const float* __restrict__ We3, const float* __restrict__ Wa1,
                  const float* __restrict__ Wa2, unsigned short* __restrict__ wst)
{
    int i = blockIdx.x * 256 + threadIdx.x;
    if (i >= WS_US) return;
    const int fs = i >> 9, l = (i >> 3) & 63, j = i & 7;
    const int kh = ((l >> 4) << 3) + j;
    const int nl = l & 15;
    float v = 0.0f;
    if (fs < 20) {
        int s = fs >> 2, w = fs & 3;
        int k = s * 32 + kh, n = w * 16 + nl;
        v = (k < 144) ? Wa1[k * 64 + n] : 0.0f;
    } else if (fs < 28) {
        int q = fs - 20, s = q >> 2, w = q & 3;
        v = Wa2[(s * 32 + kh) * 64 + (w * 16 + nl)];
    } else if (fs < 32) {
        v = 0.0f;
    } else if (fs < 176) {
        int q = fs - 32, s = q >> 4, nt = (q >> 2) & 3, w = q & 3;
        v = We1[(s * 32 + kh) * 256 + (w * 64 + nt * 16 + nl)];
    } else if (fs < 240) {
        int q = fs - 176, s = q >> 3, nt = (q >> 2) & 1, w = q & 3;
        v = We2[(s * 32 + kh) * 128 + (w * 32 + nt * 16 + nl)];
    } else if (fs < 248) {
        int q = fs - 240, s = q >> 1, nt = q & 1;
        int n = nt * 16 + nl;
        v = (n < NA) ? We3[(s * 32 + kh) * NA + n] : 0.0f;
    }
    wst[i] = f2bf(v);
}

// relu + pack + 4 b16 stores at base[0],[8],[16],[24]
__device__ __forceinline__ void wb_frag(unsigned short* base, f32x4 a)
{
    float r0 = fmaxf(a[0], 0.f), r1 = fmaxf(a[1], 0.f);
    float r2 = fmaxf(a[2], 0.f), r3 = fmaxf(a[3], 0.f);
    unsigned u01, u23;
    asm("v_cvt_pk_bf16_f32 %0, %1, %2" : "=v"(u01) : "v"(r0), "v"(r1));
    asm("v_cvt_pk_bf16_f32 %0, %1, %2" : "=v"(u23) : "v"(r2), "v"(r3));
    base[0]  = (unsigned short)u01;
    base[8]  = (unsigned short)(u01 >> 16);
    base[16] = (unsigned short)u23;
    base[24] = (unsigned short)(u23 >> 16);
}

// ---------------------------------------------------------------------------
// Fused kernel: exact R10 structure (validated 227us): 256 threads / 4 waves,
// 64-row cross-image blocks, register weight prefetch, 6 raw barriers,
// R10's interleaved staging loop (never spilled). R14 delta: __expf/__logf
// in e3 softmax only (R13 proved accuracy-safe; VALU cut with zero
// structural/register risk).
// LDS (46080 B, 3 blocks/CU):
//   Ein [0,36864) | H1 overlays [0,32768) | H2 overlays [0,16384)
//   HA1 [36864,45056) | APT [45056,46080)
// ---------------------------------------------------------------------------
__global__ __launch_bounds__(256, 3)
void fused_mfma_kernel(const float* __restrict__ last_s, const float* __restrict__ now_s,
                       const unsigned short* __restrict__ wstream,
                       const float* __restrict__ be1, const float* __restrict__ be2,
                       const float* __restrict__ be3, const float* __restrict__ ba1,
                       const float* __restrict__ ba2, const float* __restrict__ ba3,
                       const float* __restrict__ Wa3,
                       float* __restrict__ out_each, float* __restrict__ ws_alpha)
{
    __shared__ __align__(16) unsigned char smem[46080];
    unsigned short* Ein = (unsigned short*)smem;            // [4mt][9s][512]
    unsigned short* H1  = (unsigned short*)smem;            // [4mt][8s][512]
    unsigned short* H2  = (unsigned short*)smem;            // [4mt][4s][512]
    unsigned short* HA1 = (unsigned short*)(smem + 36864);  // [4mt][2s][512]
    float*          APT = (float*)(smem + 45056);           // [4][64]

    const int t    = threadIdx.x;
    const int lane = t & 63;
    const int wid  = t >> 6;
    const int g    = lane >> 4;
    const int rl   = lane & 15;
    const int row0 = blockIdx.x * 64;

#define GFRAG(fs) (*(const bf16x8*)(wstream + (size_t)(fs) * 512 + lane * 8))

    // ---- prefetch alpha + first e1 weight frags (fly during image staging) ----
    bf16x8 wa1f[5], wa2f[2];
    #pragma unroll
    for (int s = 0; s < 5; ++s) wa1f[s] = GFRAG(s * 4 + wid);
    #pragma unroll
    for (int s = 0; s < 2; ++s) wa2f[s] = GFRAG(20 + s * 4 + wid);
    bf16x8 wA[4], wB[4], wC[4];
    #pragma unroll
    for (int nt = 0; nt < 4; ++nt) wA[nt] = GFRAG(32 + 0 * 16 + nt * 4 + wid);
    #pragma unroll
    for (int nt = 0; nt < 4; ++nt) wB[nt] = GFRAG(32 + 1 * 16 + nt * 4 + wid);
    #pragma unroll
    for (int nt = 0; nt < 4; ++nt) wC[nt] = GFRAG(32 + 2 * 16 + nt * 4 + wid);

    // ---- phase 0: per-row patch gather -> Ein fragment layout (cvt_pk) ----
    // idx = r*36 + q over 64 rows x 36 float4-slots (144 features / 4).
    // Row r -> global row R = row0+r -> image R/49, patch R%49.  (R10 form)
    {
        #pragma unroll
        for (int it = 0; it < 9; ++it) {
            const int idx = t + it * 256;          // 9*256 == 2304 exactly
            const int r   = idx / 36;
            const int q   = idx - r * 36;
            const int R   = row0 + r;
            const int im  = R / 49;
            const int p   = R - im * 49;
            const int pi  = p / 7,  pj  = p - pi * 7;
            const int fr  = q / 3,  fc4 = q - fr * 3;
            const size_t base = (size_t)im * 7056 + (pi * 12 + fr) * 84 + pj * 12 + fc4 * 4;
            const float4 n4 = *(const float4*)(now_s + base);
            const float4 l4 = *(const float4*)(last_s + base);
            const float k255 = 1.0f / 255.0f;
            float d0 = (n4.x - l4.x) * k255, d1 = (n4.y - l4.y) * k255;
            float d2 = (n4.z - l4.z) * k255, d3 = (n4.w - l4.w) * k255;
            float w0 = n4.x * k255, w1 = n4.y * k255;
            float w2 = n4.z * k255, w3 = n4.w * k255;
            unsigned da, db, wa, wb;
            asm("v_cvt_pk_bf16_f32 %0, %1, %2" : "=v"(da) : "v"(d0), "v"(d1));
            asm("v_cvt_pk_bf16_f32 %0, %1, %2" : "=v"(db) : "v"(d2), "v"(d3));
            asm("v_cvt_pk_bf16_f32 %0, %1, %2" : "=v"(wa) : "v"(w0), "v"(w1));
            asm("v_cvt_pk_bf16_f32 %0, %1, %2" : "=v"(wb) : "v"(w2), "v"(w3));
            const int wp = r >> 4, rp = r & 15;
            const int f  = fr * 12 + fc4 * 4;
            const int s1 = f >> 5, g1 = (f >> 3) & 3, j1 = f & 7;
            *(uint2*)(Ein + (wp * 9 + s1) * 512 + g1 * 128 + rp * 8 + j1) = (uint2){da, db};
            const int k2 = 144 + f;
            const int s2 = k2 >> 5, g2 = (k2 >> 3) & 3, j2 = k2 & 7;
            *(uint2*)(Ein + (wp * 9 + s2) * 512 + g2 * 128 + rp * 8 + j2) = (uint2){wa, wb};
        }
    }
    RAWBAR();   // B1: Ein ready (all 64 rows valid)

    // ================= alpha layer 1 (no barrier after; e1 follows) =========
    const int colA = wid * 16 + rl;
    {
        const float b1 = ba1[colA];
        f32x4 accA[4];
        #pragma unroll
        for (int mt = 0; mt < 4; ++mt) accA[mt] = (f32x4){b1, b1, b1, b1};
        #pragma unroll
        for (int sa = 0; sa < 5; ++sa) {
            int ok = 144 + sa * 32 + g * 8;
            if (ok > 280) ok = 280;   // tail: weight rows zero; clamp into valid data
            #pragma unroll
            for (int mt = 0; mt < 4; ++mt) {
                const bf16x8 af = *(const bf16x8*)(Ein + (mt * 9 + (ok >> 5)) * 512 +
                                                   ((ok >> 3) & 3) * 128 + rl * 8);
                accA[mt] = MF(af, wa1f[sa], accA[mt]);
            }
        }
        const int sA  = wid >> 1;
        const int hiA = (wid & 1) * 2 + (rl >> 3);
        const int jA  = rl & 7;
        #pragma unroll
        for (int mt = 0; mt < 4; ++mt)
            wb_frag(HA1 + (mt * 2 + sA) * 512 + hiA * 128 + g * 32 + jA, accA[mt]);
    }

    // ================= e layer 1 part 1 (steps 0..4) =================
    f32x4 acc1[4][4];
    #pragma unroll
    for (int nt = 0; nt < 4; ++nt) {
        const float b = be1[wid * 64 + nt * 16 + rl];
        #pragma unroll
        for (int mt = 0; mt < 4; ++mt) acc1[mt][nt] = (f32x4){b, b, b, b};
    }

#define E1_STEP(W, s, sn) do { \
    const bf16x8 x0_ = *(const bf16x8*)(Ein + (0 * 9 + (s)) * 512 + lane * 8); \
    const bf16x8 x1_ = *(const bf16x8*)(Ein + (1 * 9 + (s)) * 512 + lane * 8); \
    const bf16x8 x2_ = *(const bf16x8*)(Ein + (2 * 9 + (s)) * 512 + lane * 8); \
    const bf16x8 x3_ = *(const bf16x8*)(Ein + (3 * 9 + (s)) * 512 + lane * 8); \
    _Pragma("unroll") \
    for (int nt = 0; nt < 4; ++nt) { \
        acc1[0][nt] = MF(x0_, W[nt], acc1[0][nt]); \
        acc1[1][nt] = MF(x1_, W[nt], acc1[1][nt]); \
        acc1[2][nt] = MF(x2_, W[nt], acc1[2][nt]); \
        acc1[3][nt] = MF(x3_, W[nt], acc1[3][nt]); \
    } \
    if ((sn) <= 8) { \
        _Pragma("unroll") \
        for (int nt = 0; nt < 4; ++nt) W[nt] = GFRAG(32 + (sn) * 16 + nt * 4 + wid); \
    } \
} while (0)

    E1_STEP(wA, 0, 3); E1_STEP(wB, 1, 4); E1_STEP(wC, 2, 5);
    E1_STEP(wA, 3, 6); E1_STEP(wB, 4, 7);

    RAWBAR();   // B2: HA1 visible (issued after 5 e1 steps of useful work)

    // ================= alpha layer 2 + fused layer 3 =================
    {
        const float b2 = ba2[colA];
        const float w3 = Wa3[colA];
        f32x4 accB[4];
        #pragma unroll
        for (int mt = 0; mt < 4; ++mt) accB[mt] = (f32x4){b2, b2, b2, b2};
        #pragma unroll
        for (int s = 0; s < 2; ++s) {
            #pragma unroll
            for (int mt = 0; mt < 4; ++mt) {
                const bf16x8 af = *(const bf16x8*)(HA1 + (mt * 2 + s) * 512 + lane * 8);
                accB[mt] = MF(af, wa2f[s], accB[mt]);
            }
        }
        #pragma unroll
        for (int mt = 0; mt < 4; ++mt) {
            #pragma unroll
            for (int r = 0; r < 4; ++r) {
                float v = fmaxf(accB[mt][r], 0.0f) * w3;
                v += __shfl_xor(v, 1); v += __shfl_xor(v, 2);
                v += __shfl_xor(v, 4); v += __shfl_xor(v, 8);
                if (rl == 0) APT[wid * 64 + mt * 16 + g * 4 + r] = v;
            }
        }
    }

    // ================= e layer 1 part 2 (steps 5..8) =================
    E1_STEP(wC, 5, 8); E1_STEP(wA, 6, 9); E1_STEP(wB, 7, 9); E1_STEP(wC, 8, 9);
#undef E1_STEP

    // e2 weight prefetch (flies across B3 + H1 writes + B4)
    bf16x8 vA[2], vB[2], vC[2];
    #pragma unroll
    for (int nt = 0; nt < 2; ++nt) vA[nt] = GFRAG(176 + 0 * 8 + nt * 4 + wid);
    #pragma unroll
    for (int nt = 0; nt < 2; ++nt) vB[nt] = GFRAG(176 + 1 * 8 + nt * 4 + wid);
    #pragma unroll
    for (int nt = 0; nt < 2; ++nt) vC[nt] = GFRAG(176 + 2 * 8 + nt * 4 + wid);

    RAWBAR();   // B3: APT visible + all Ein reads done -> H1 may overlay

    // alpha logits -> ws_alpha (all 64 rows valid, global flattened index)
    if (t < 64)
        ws_alpha[row0 + t] = APT[t] + APT[64 + t] + APT[128 + t] + APT[192 + t] + ba3[0];

    // H1 fragment writes (relu, cvt_pk)
    #pragma unroll
    for (int mt = 0; mt < 4; ++mt) {
        #pragma unroll
        for (int nt = 0; nt < 4; ++nt) {
            const int col = wid * 64 + nt * 16 + rl;
            wb_frag(H1 + (mt * 8 + (col >> 5)) * 512 + ((col >> 3) & 3) * 128 +
                    g * 32 + (col & 7), acc1[mt][nt]);
        }
    }
    RAWBAR();   // B4: H1 ready

    // ================= e layer 2: 256 -> 128 =================
    f32x4 acc2[4][2];
    #pragma unroll
    for (int nt = 0; nt < 2; ++nt) {
        const float b = be2[wid * 32 + nt * 16 + rl];
        #pragma unroll
        for (int mt = 0; mt < 4; ++mt) acc2[mt][nt] = (f32x4){b, b, b, b};
    }

#define E2_STEP(V, s2, sn) do { \
    const bf16x8 x0_ = *(const bf16x8*)(H1 + (0 * 8 + (s2)) * 512 + lane * 8); \
    const bf16x8 x1_ = *(const bf16x8*)(H1 + (1 * 8 + (s2)) * 512 + lane * 8); \
    const bf16x8 x2_ = *(const bf16x8*)(H1 + (2 * 8 + (s2)) * 512 + lane * 8); \
    const bf16x8 x3_ = *(const bf16x8*)(H1 + (3 * 8 + (s2)) * 512 + lane * 8); \
    _Pragma("unroll") \
    for (int nt = 0; nt < 2; ++nt) { \
        acc2[0][nt] = MF(x0_, V[nt], acc2[0][nt]); \
        acc2[1][nt] = MF(x1_, V[nt], acc2[1][nt]); \
        acc2[2][nt] = MF(x2_, V[nt], acc2[2][nt]); \
        acc2[3][nt] = MF(x3_, V[nt], acc2[3][nt]); \
    } \
    if ((sn) <= 7) { \
        _Pragma("unroll") \
        for (int nt = 0; nt < 2; ++nt) V[nt] = GFRAG(176 + (sn) * 8 + nt * 4 + wid); \
    } \
} while (0)

    E2_STEP(vA, 0, 3); E2_STEP(vB, 1, 4); E2_STEP(vC, 2, 5);
    E2_STEP(vA, 3, 6); E2_STEP(vB, 4, 7); E2_STEP(vC, 5, 8);
    E2_STEP(vA, 6, 8); E2_STEP(vB, 7, 8);
#undef E2_STEP

    // e3 weight frags (in flight across barriers)
    bf16x8 w3f[8];
    #pragma unroll
    for (int q = 0; q < 8; ++q) w3f[q] = GFRAG(240 + q);

    RAWBAR();   // B5: all H1 reads done -> H2 may overlay

    // H2 fragment writes (relu, cvt_pk)
    #pragma unroll
    for (int mt = 0; mt < 4; ++mt) {
        #pragma unroll
        for (int nt = 0; nt < 2; ++nt) {
            const int c2 = nt * 16 + rl;
            wb_frag(H2 + (mt * 4 + wid) * 512 + ((c2 >> 3) & 3) * 128 +
                    g * 32 + (c2 & 7), acc2[mt][nt]);
        }
    }
    RAWBAR();   // B6: H2 ready

    // ================= e layer 3: 128 -> 18 (+log_softmax, fast exp/log) ====
    {
        f32x4 acc3[2];
        #pragma unroll
        for (int nt = 0; nt < 2; ++nt) {
            const int col = nt * 16 + rl;
            const float b = (col < NA) ? be3[col] : 0.0f;
            acc3[nt] = (f32x4){b, b, b, b};
        }
        #pragma unroll
        for (int s = 0; s < 4; ++s) {
            const bf16x8 af = *(const bf16x8*)(H2 + (wid * 4 + s) * 512 + lane * 8);
            acc3[0] = MF(af, w3f[s * 2 + 0], acc3[0]);
            acc3[1] = MF(af, w3f[s * 2 + 1], acc3[1]);
        }
        const bool v1 = (rl < 2);
        #pragma unroll
        for (int r = 0; r < 4; ++r) {
            const int prow = row0 + wid * 16 + g * 4 + r;   // always valid
            float x0 = acc3[0][r];
            float x1 = acc3[1][r];
            float m = fmaxf(x0, v1 ? x1 : -3.0e38f);
            m = fmaxf(m, __shfl_xor(m, 1)); m = fmaxf(m, __shfl_xor(m, 2));
            m = fmaxf(m, __shfl_xor(m, 4)); m = fmaxf(m, __shfl_xor(m, 8));
            float sm = __expf(x0 - m) + (v1 ? __expf(x1 - m) : 0.0f);
            sm += __shfl_xor(sm, 1); sm += __shfl_xor(sm, 2);
            sm += __shfl_xor(sm, 4); sm += __shfl_xor(sm, 8);
            const float L = m + __logf(sm);
            float* o = out_each + (size_t)prow * NA;
            o[rl] = x0 - L;
            if (v1) o[16 + rl] = x1 - L;
        }
    }
#undef GFRAG
}

// ---------------------------------------------------------------------------
// Per-image alpha combine (validated structure; fast transcendentals).
// ---------------------------------------------------------------------------
__global__ __launch_bounds__(64)
void alpha_combine_kernel(const float* __restrict__ ws_alpha,
                          const float* __restrict__ out_each,
                          float* __restrict__ out_probs,
                          float* __restrict__ ws_ent)
{
    const int b = blockIdx.x;
    const int lane = threadIdx.x;

    float lg = (lane < NPCH) ? ws_alpha[b * NPCH + lane] : -3.0e38f;
    float m = lg;
    #pragma unroll
    for (int off = 32; off > 0; off >>= 1) m = fmaxf(m, __shfl_xor(m, off, 64));
    float ex = (lane < NPCH) ? __expf(lg - m) : 0.0f;
    float s = ex;
    #pragma unroll
    for (int off = 32; off > 0; off >>= 1) s += __shfl_xor(s, off, 64);
    const float ls = __logf(s);
    const float alpha = ex / s;

    float ent = (lane < NPCH) ? alpha * (lg - m - ls) : 0.0f;
    #pragma unroll
    for (int off = 32; off > 0; off >>= 1) ent += __shfl_xor(ent, off, 64);
    if (lane == 0) ws_ent[b] = ent;

    float acc = 0.0f;
    const float* eb = out_each + (size_t)b * NPCH * NA;
    for (int p = 0; p < NPCH; ++p) {
        const float ap = __shfl(alpha, p, 64);
        if (lane < NA) acc += ap * eb[p * NA + lane];
    }
    float mm = (lane < NA) ? acc : -3.0e38f;
    #pragma unroll
    for (int off = 32; off > 0; off >>= 1) mm = fmaxf(mm, __shfl_xor(mm, off, 64));
    float ee = (lane < NA) ? __expf(acc - mm) : 0.0f;
    #pragma unroll
    for (int off = 32; off > 0; off >>= 1) ee += __shfl_xor(ee, off, 64);
    if (lane < NA) out_probs[b * NA + lane] = acc - mm - __logf(ee);
}

__global__ __launch_bounds__(256)
void ent_reduce_kernel(const float* __restrict__ ws_ent, float* __restrict__ out_scalar)
{
    float s = 0.0f;
    for (int i = threadIdx.x; i < NB; i += 256) s += ws_ent[i];
    #pragma unroll
    for (int off = 32; off > 0; off >>= 1) s += __shfl_xor(s, off, 64);
    __shared__ float ps[4];
    if ((threadIdx.x & 63) == 0) ps[threadIdx.x >> 6] = s;
    __syncthreads();
    if (threadIdx.x == 0)
        out_scalar[0] = (ps[0] + ps[1] + ps[2] + ps[3]) * (1.0f / NB);
}

extern "C" void kernel_launch(void* const* d_in, const int* in_sizes, int n_in,
                              void* d_out, int out_size, void* d_ws, size_t ws_size,
                              hipStream_t stream)
{
    (void)in_sizes; (void)n_in; (void)out_size; (void)ws_size;

    const float* last_s = (const float*)d_in[0];
    const float* now_s  = (const float*)d_in[1];
    const float* We1 = (const float*)d_in[2];  const float* be1 = (const float*)d_in[3];
    const float* We2 = (const float*)d_in[4];  const float* be2 = (const float*)d_in[5];
    const float* We3 = (const float*)d_in[6];  const float* be3 = (const float*)d_in[7];
    const float* Wa1 = (const float*)d_in[8];  const float* ba1 = (const float*)d_in[9];
    const float* Wa2 = (const float*)d_in[10]; const float* ba2 = (const float*)d_in[11];
    const float* Wa3 = (const float*)d_in[12]; const float* ba3 = (const float*)d_in[13];

    float* out = (float*)d_out;
    float* out_probs = out;                    // [B,18]
    float* out_ent   = out + NB * NA;          // scalar
    float* out_each  = out + NB * NA + 1;      // [B,49,18]

    float* ws_alpha = (float*)d_ws;                          // [TOTAL]
    float* ws_ent   = ws_alpha + TOTAL;                      // [NB]
    unsigned short* wst = (unsigned short*)(ws_ent + NB);    // weight stream (256KB)

    prep_weights<<<dim3((WS_US + 255) / 256), dim3(256), 0, stream>>>(
        We1, We2, We3, Wa1, Wa2, wst);

    fused_mfma_kernel<<<dim3(NBLK), dim3(256), 0, stream>>>(
        last_s, now_s, wst, be1, be2, be3, ba1, ba2, ba3, Wa3,
        out_each, ws_alpha);

    alpha_combine_kernel<<<dim3(NB), dim3(64), 0, stream>>>(
        ws_alpha, out_each, out_probs, ws_ent);

    ent_reduce_kernel<<<dim3(1), dim3(256), 0, stream>>>(ws_ent, out_ent);
}